// Round 1
// baseline (444.337 us; speedup 1.0000x reference)
//
#include <hip/hip_runtime.h>
#include <math.h>

typedef __bf16 bf16;
typedef __bf16 bf16x8 __attribute__((ext_vector_type(8)));
typedef __bf16 bf16x4 __attribute__((ext_vector_type(4)));
typedef float f32x4 __attribute__((ext_vector_type(4)));

// Problem constants
// B=2, C=512, L=4096 (=64*64), NH=4, HD=128, GROUPS=32, ch/group=16, group size=65536

// ---------------- weight conversion fp32 -> bf16 ----------------
__global__ void k_convert_w(const float* __restrict__ wqkv, const float* __restrict__ wproj,
                            bf16* __restrict__ wqkv_b, bf16* __restrict__ wproj_b) {
    int i = blockIdx.x * blockDim.x + threadIdx.x;   // float4 index
    const int n1 = (1536 * 512) / 4;
    float4 v;
    bf16* dst;
    if (i < n1) { v = ((const float4*)wqkv)[i];      dst = wqkv_b + (size_t)i * 4; }
    else        { v = ((const float4*)wproj)[i - n1]; dst = wproj_b + (size_t)(i - n1) * 4; }
    bf16x4 o;
    o[0] = (bf16)v.x; o[1] = (bf16)v.y; o[2] = (bf16)v.z; o[3] = (bf16)v.w;
    *(bf16x4*)dst = o;
}

// ---------------- GroupNorm ----------------
// 256 blocks: 4 partial blocks per (b,group); each reduces 16384 contiguous floats.
__global__ void k_gn_partial(const float* __restrict__ x, float* __restrict__ part) {
    int blk = blockIdx.x;
    int grp = blk >> 2, p = blk & 3;
    const float4* src = (const float4*)(x + (size_t)grp * 65536 + (size_t)p * 16384);
    float s = 0.f, ss = 0.f;
    for (int it = 0; it < 16; ++it) {
        float4 v = src[threadIdx.x + it * 256];
        s  += v.x + v.y + v.z + v.w;
        ss += v.x * v.x + v.y * v.y + v.z * v.z + v.w * v.w;
    }
    for (int off = 32; off; off >>= 1) { s += __shfl_down(s, off); ss += __shfl_down(ss, off); }
    __shared__ float rs[4], rss[4];
    int wave = threadIdx.x >> 6;
    if ((threadIdx.x & 63) == 0) { rs[wave] = s; rss[wave] = ss; }
    __syncthreads();
    if (threadIdx.x == 0) {
        float S = rs[0] + rs[1] + rs[2] + rs[3];
        float SS = rss[0] + rss[1] + rss[2] + rss[3];
        part[(grp * 4 + p) * 2]     = S;
        part[(grp * 4 + p) * 2 + 1] = SS;
    }
}

__global__ void k_gn_final(const float* __restrict__ part, float* __restrict__ gstats) {
    int g = threadIdx.x;   // 64 groups total (b*32+g)
    float S = 0.f, SS = 0.f;
    for (int p = 0; p < 4; ++p) { S += part[(g * 4 + p) * 2]; SS += part[(g * 4 + p) * 2 + 1]; }
    float mean = S * (1.f / 65536.f);
    float var  = SS * (1.f / 65536.f) - mean * mean;
    gstats[g * 2]     = mean;
    gstats[g * 2 + 1] = rsqrtf(var + 1e-5f);
}

__global__ void k_gn_norm(const float* __restrict__ x, const float* __restrict__ gw,
                          const float* __restrict__ gb, const float* __restrict__ gstats,
                          bf16* __restrict__ xn) {
    int i = blockIdx.x * blockDim.x + threadIdx.x;   // float4 index
    for (int it = 0; it < 4; ++it, i += 262144) {
        int flat = i * 4;
        int c = (flat >> 12) & 511;
        int b = flat >> 21;
        int g = (b << 5) | (c >> 4);
        float mean = gstats[g * 2], rstd = gstats[g * 2 + 1];
        float ga = gw[c] * rstd;
        float be = gb[c] - mean * ga;
        float4 v = ((const float4*)x)[i];
        bf16x4 o;
        o[0] = (bf16)(v.x * ga + be);
        o[1] = (bf16)(v.y * ga + be);
        o[2] = (bf16)(v.z * ga + be);
        o[3] = (bf16)(v.w * ga + be);
        *(bf16x4*)(xn + (size_t)flat) = o;
    }
}

// ---------------- bf16 MFMA GEMM: C[bz] = A[M,K] * B[bz][K,N] + bias ----------------
// outb!=null: bf16 out. outf!=null: fp32 out with += resid.
__global__ __launch_bounds__(256) void k_gemm(
    const bf16* __restrict__ A, const bf16* __restrict__ Bm, const float* __restrict__ bias,
    bf16* __restrict__ outb, float* __restrict__ outf, const float* __restrict__ resid,
    int M, int N, int K) {
    __shared__ bf16 sA[128 * 72];    // [m][k], stride 72 (144B, 16B-aligned, 2-way banks = free)
    __shared__ bf16 sBt[128 * 72];   // [n][k]
    int bz = blockIdx.z;
    const bf16* Bp = Bm + (size_t)bz * K * N;
    int m0 = blockIdx.y * 128, n0 = blockIdx.x * 128;
    int tid = threadIdx.x;
    int lane = tid & 63, wave = tid >> 6;
    int lo = lane & 15, quad = lane >> 4;
    int mw = (wave >> 1) * 64, nw = (wave & 1) * 64;
    f32x4 acc[4][4] = {};
    int a_m = tid >> 3, a_k = (tid & 7) * 8;
    int b_k = tid >> 4, b_n8 = tid & 15;
    for (int k0 = 0; k0 < K; k0 += 64) {
        for (int i = 0; i < 4; ++i) {
            int m = a_m + i * 32;
            bf16x8 v = *(const bf16x8*)(A + (size_t)(m0 + m) * K + k0 + a_k);
            *(bf16x8*)&sA[m * 72 + a_k] = v;
        }
        for (int i = 0; i < 4; ++i) {
            int k = b_k + i * 16;
            bf16x8 v = *(const bf16x8*)(Bp + (size_t)(k0 + k) * N + n0 + b_n8 * 8);
            for (int j = 0; j < 8; ++j) sBt[(b_n8 * 8 + j) * 72 + k] = v[j];
        }
        __syncthreads();
        for (int kk = 0; kk < 2; ++kk) {
            bf16x8 af[4], bfr[4];
            for (int t = 0; t < 4; ++t)
                af[t] = *(const bf16x8*)&sA[(mw + t * 16 + lo) * 72 + kk * 32 + quad * 8];
            for (int t = 0; t < 4; ++t)
                bfr[t] = *(const bf16x8*)&sBt[(nw + t * 16 + lo) * 72 + kk * 32 + quad * 8];
            for (int mt = 0; mt < 4; ++mt)
                for (int nt = 0; nt < 4; ++nt)
                    acc[mt][nt] = __builtin_amdgcn_mfma_f32_16x16x32_bf16(af[mt], bfr[nt], acc[mt][nt], 0, 0, 0);
        }
        __syncthreads();
    }
    for (int mt = 0; mt < 4; ++mt) {
        int row_base = m0 + mw + mt * 16 + quad * 4;
        for (int nt = 0; nt < 4; ++nt) {
            int col = n0 + nw + nt * 16 + lo;
            for (int r = 0; r < 4; ++r) {
                int row = row_base + r;
                float v = acc[mt][nt][r] + bias[row];
                size_t idx = (size_t)bz * M * N + (size_t)row * N + col;
                if (outf) outf[idx] = v + resid[idx];
                else      outb[idx] = (bf16)v;
            }
        }
    }
}

// ---------------- flash attention ----------------
// grid (L/64, NH, B), block 256. qkv: [b][1536][4096] bf16 (q,k,v each 512 rows; head = 128 rows)
__global__ __launch_bounds__(256) void k_attn(const bf16* __restrict__ qkv, bf16* __restrict__ attn_out) {
    __shared__ __align__(16) char smem[63232];
    bf16*  qt = (bf16*)smem;                 // 64 x 136 (region reused below)
    float* sS = (float*)smem;                // 64 x 68 fp32
    bf16*  sP = (bf16*)(smem + 17408);       // 64 x 72
    bf16*  kt = (bf16*)(smem + 26624);       // 64 x 136  [e][c]
    bf16*  sV = (bf16*)(smem + 44032);       // 128 x 72  [c][e]
    float* sM  = (float*)(smem + 62464);
    float* sL  = sM + 64;
    float* sAl = sM + 128;
    int b = blockIdx.z, head = blockIdx.y;
    int d0 = blockIdx.x * 64;
    const bf16* qp = qkv + ((size_t)(b * 1536 + head * 128)) * 4096;
    const bf16* kp = qkv + ((size_t)(b * 1536 + 512 + head * 128)) * 4096;
    const bf16* vp = qkv + ((size_t)(b * 1536 + 1024 + head * 128)) * 4096;
    int tid = threadIdx.x;
    int lane = tid & 63, wave = tid >> 6;
    int lo = lane & 15, quad = lane >> 4;
    int sc = tid >> 3, sc8 = (tid & 7) * 8;
    const float scale = 0.08838834764831845f;   // 1/sqrt(128)
    // stage Q^T (scaled) into qt[d][c]
    for (int i = 0; i < 4; ++i) {
        int c = sc + i * 32;
        bf16x8 v = *(const bf16x8*)(qp + (size_t)c * 4096 + d0 + sc8);
        for (int j = 0; j < 8; ++j) qt[(sc8 + j) * 136 + c] = (bf16)((float)v[j] * scale);
    }
    if (tid < 64) { sM[tid] = -1e30f; sL[tid] = 0.f; }
    __syncthreads();
    int dw = wave * 16;
    bf16x8 qf[4];
    for (int kk = 0; kk < 4; ++kk)
        qf[kk] = *(const bf16x8*)&qt[(dw + lo) * 136 + kk * 32 + quad * 8];
    f32x4 oacc[2][4] = {};
    __syncthreads();   // qt reads complete; region becomes sS/sP
    int row = tid >> 2, q4 = tid & 3;
    for (int e0 = 0; e0 < 4096; e0 += 64) {
        // stage K^T -> kt[e][c], V -> sV[c][e]
        for (int i = 0; i < 4; ++i) {
            int c = sc + i * 32;
            bf16x8 v = *(const bf16x8*)(kp + (size_t)c * 4096 + e0 + sc8);
            for (int j = 0; j < 8; ++j) kt[(sc8 + j) * 136 + c] = v[j];
        }
        for (int i = 0; i < 4; ++i) {
            int c = sc + i * 32;
            *(bf16x8*)&sV[c * 72 + sc8] = *(const bf16x8*)(vp + (size_t)c * 4096 + e0 + sc8);
        }
        __syncthreads();
        // S = Q^T K : each wave computes 16 rows (d) x 64 cols (e)
        for (int nt = 0; nt < 4; ++nt) {
            f32x4 s = {};
            for (int kk = 0; kk < 4; ++kk) {
                bf16x8 kf = *(const bf16x8*)&kt[(nt * 16 + lo) * 136 + kk * 32 + quad * 8];
                s = __builtin_amdgcn_mfma_f32_16x16x32_bf16(qf[kk], kf, s, 0, 0, 0);
            }
            for (int r = 0; r < 4; ++r)
                sS[(dw + quad * 4 + r) * 68 + nt * 16 + lo] = s[r];
        }
        __syncthreads();
        // online softmax: 4 threads per row
        float* rp = &sS[row * 68 + q4 * 16];
        float mx = rp[0];
        for (int j = 1; j < 16; ++j) mx = fmaxf(mx, rp[j]);
        mx = fmaxf(mx, __shfl_xor(mx, 1));
        mx = fmaxf(mx, __shfl_xor(mx, 2));
        float m_old = sM[row];
        float m_new = fmaxf(m_old, mx);
        float sum = 0.f;
        bf16* pp = &sP[row * 72 + q4 * 16];
        for (int j = 0; j < 16; ++j) {
            float p = __expf(rp[j] - m_new);
            sum += p;
            pp[j] = (bf16)p;
        }
        sum += __shfl_xor(sum, 1);
        sum += __shfl_xor(sum, 2);
        if (q4 == 0) {
            sAl[row] = __expf(m_old - m_new);
            sM[row]  = m_new;
            sL[row]  = sL[row] * __expf(m_old - m_new) + sum;
        }
        __syncthreads();
        // O[c][d] (+= V * P^T), each wave owns 32 c-rows
        int cw = wave * 32;
        for (int dt = 0; dt < 4; ++dt) {
            float al = sAl[dt * 16 + lo];
            for (int ct = 0; ct < 2; ++ct) {
                f32x4 o = oacc[ct][dt];
                o *= al;
                for (int kk = 0; kk < 2; ++kk) {
                    bf16x8 vf = *(const bf16x8*)&sV[(cw + ct * 16 + lo) * 72 + kk * 32 + quad * 8];
                    bf16x8 pf = *(const bf16x8*)&sP[(dt * 16 + lo) * 72 + kk * 32 + quad * 8];
                    o = __builtin_amdgcn_mfma_f32_16x16x32_bf16(vf, pf, o, 0, 0, 0);
                }
                oacc[ct][dt] = o;
            }
        }
        __syncthreads();
    }
    int cw = wave * 32;
    for (int dt = 0; dt < 4; ++dt) {
        float li = 1.f / sL[dt * 16 + lo];
        for (int ct = 0; ct < 2; ++ct) {
            for (int r = 0; r < 4; ++r) {
                int c = cw + ct * 16 + quad * 4 + r;
                int d = d0 + dt * 16 + lo;
                attn_out[((size_t)(b * 512 + head * 128 + c)) * 4096 + d] = (bf16)(oacc[ct][dt][r] * li);
            }
        }
    }
}

// ---------------- launcher ----------------
extern "C" void kernel_launch(void* const* d_in, const int* in_sizes, int n_in,
                              void* d_out, int out_size, void* d_ws, size_t ws_size,
                              hipStream_t stream) {
    const float* x      = (const float*)d_in[0];
    const float* gn_w   = (const float*)d_in[1];
    const float* gn_b   = (const float*)d_in[2];
    const float* w_qkv  = (const float*)d_in[3];
    const float* b_qkv  = (const float*)d_in[4];
    const float* w_proj = (const float*)d_in[5];
    const float* b_proj = (const float*)d_in[6];
    float* out = (float*)d_out;
    char* ws = (char*)d_ws;
    bf16* wqkv_b  = (bf16*)(ws + 0);          // 1536*512*2      = 1,572,864
    bf16* wproj_b = (bf16*)(ws + 1572864);    // 512*512*2       =   524,288
    bf16* xn_b    = (bf16*)(ws + 2097152);    // 2*512*4096*2    = 8,388,608
    bf16* qkv_b   = (bf16*)(ws + 10485760);   // 2*1536*4096*2   = 25,165,824
    bf16* attn_b  = (bf16*)(ws + 35651584);   // 2*512*4096*2    = 8,388,608
    float* part   = (float*)(ws + 44040192);  // 64*4*2*4        = 2,048
    float* gstats = (float*)(ws + 44042240);  // 64*2*4          = 512

    k_convert_w<<<1024, 256, 0, stream>>>(w_qkv, w_proj, wqkv_b, wproj_b);
    k_gn_partial<<<256, 256, 0, stream>>>(x, part);
    k_gn_final<<<1, 64, 0, stream>>>(part, gstats);
    k_gn_norm<<<1024, 256, 0, stream>>>(x, gn_w, gn_b, gstats, xn_b);
    // qkv: [1536,512] x [512,4096] per batch
    k_gemm<<<dim3(32, 12, 2), 256, 0, stream>>>(wqkv_b, xn_b, b_qkv, qkv_b, nullptr, nullptr, 1536, 4096, 512);
    k_attn<<<dim3(64, 4, 2), 256, 0, stream>>>(qkv_b, attn_b);
    // proj: [512,512] x [512,4096] per batch, + bias + residual -> fp32 out
    k_gemm<<<dim3(32, 4, 2), 256, 0, stream>>>(wproj_b, attn_b, b_proj, nullptr, out, x, 512, 4096, 512);
}

// Round 2
// 368.739 us; speedup vs baseline: 1.2050x; 1.2050x over previous
//
#include <hip/hip_runtime.h>
#include <math.h>

typedef __bf16 bf16;
typedef __bf16 bf16x8 __attribute__((ext_vector_type(8)));
typedef __bf16 bf16x4 __attribute__((ext_vector_type(4)));
typedef float f32x4 __attribute__((ext_vector_type(4)));

// B=2, C=512, L=4096, NH=4, HD=128, GROUPS=32. K of every GEMM = 512.
#define QSCALE (0.08838834764831845f * 1.4426950408889634f)  // 1/sqrt(128) * log2(e)

__device__ __forceinline__ void gll16(const bf16* g, bf16* l) {
    __builtin_amdgcn_global_load_lds((const __attribute__((address_space(1))) void*)g,
                                     (__attribute__((address_space(3))) void*)l, 16, 0, 0);
}

// ---------------- weight conversion fp32 -> bf16 ----------------
__global__ void k_convert_w(const float* __restrict__ wqkv, const float* __restrict__ wproj,
                            bf16* __restrict__ wqkv_b, bf16* __restrict__ wproj_b) {
    int i = blockIdx.x * blockDim.x + threadIdx.x;   // float4 index
    const int n1 = (1536 * 512) / 4;
    float4 v;
    bf16* dst;
    if (i < n1) { v = ((const float4*)wqkv)[i];      dst = wqkv_b + (size_t)i * 4; }
    else        { v = ((const float4*)wproj)[i - n1]; dst = wproj_b + (size_t)(i - n1) * 4; }
    bf16x4 o;
    o[0] = (bf16)v.x; o[1] = (bf16)v.y; o[2] = (bf16)v.z; o[3] = (bf16)v.w;
    *(bf16x4*)dst = o;
}

// ---------------- GroupNorm stats ----------------
__global__ void k_gn_partial(const float* __restrict__ x, float* __restrict__ part) {
    int blk = blockIdx.x;
    int grp = blk >> 2, p = blk & 3;
    const float4* src = (const float4*)(x + (size_t)grp * 65536 + (size_t)p * 16384);
    float s = 0.f, ss = 0.f;
    for (int it = 0; it < 16; ++it) {
        float4 v = src[threadIdx.x + it * 256];
        s  += v.x + v.y + v.z + v.w;
        ss += v.x * v.x + v.y * v.y + v.z * v.z + v.w * v.w;
    }
    for (int off = 32; off; off >>= 1) { s += __shfl_down(s, off); ss += __shfl_down(ss, off); }
    __shared__ float rs[4], rss[4];
    int wave = threadIdx.x >> 6;
    if ((threadIdx.x & 63) == 0) { rs[wave] = s; rss[wave] = ss; }
    __syncthreads();
    if (threadIdx.x == 0) {
        part[(grp * 4 + p) * 2]     = rs[0] + rs[1] + rs[2] + rs[3];
        part[(grp * 4 + p) * 2 + 1] = rss[0] + rss[1] + rss[2] + rss[3];
    }
}

__global__ void k_gn_final(const float* __restrict__ part, float* __restrict__ gstats) {
    int g = threadIdx.x;   // 64 groups total (b*32+g)
    float S = 0.f, SS = 0.f;
    for (int p = 0; p < 4; ++p) { S += part[(g * 4 + p) * 2]; SS += part[(g * 4 + p) * 2 + 1]; }
    float mean = S * (1.f / 65536.f);
    float var  = SS * (1.f / 65536.f) - mean * mean;
    gstats[g * 2]     = mean;
    gstats[g * 2 + 1] = rsqrtf(var + 1e-5f);
}

// ---------------- GN normalize + transpose: x[b][c][l] -> xn_t[b][l][c] bf16 ----------------
__global__ __launch_bounds__(256) void k_gn_norm_t(const float* __restrict__ x, const float* __restrict__ gw,
                                                   const float* __restrict__ gb, const float* __restrict__ gstats,
                                                   bf16* __restrict__ xn_t) {
    __shared__ float sX[64 * 69];
    int b = blockIdx.z, c0 = blockIdx.y * 64, l0 = blockIdx.x * 64;
    int t = threadIdx.x;
    int cr = t >> 4, lq = t & 15;
    const float* xp = x + ((size_t)(b * 512 + c0)) * 4096 + l0;
    for (int i = 0; i < 4; ++i) {
        int c = cr + i * 16;
        int cg = c0 + c;
        int g = b * 32 + (cg >> 4);
        float mean = gstats[g * 2], rstd = gstats[g * 2 + 1];
        float ga = gw[cg] * rstd;
        float be = gb[cg] - mean * ga;
        float4 v = *(const float4*)(xp + (size_t)c * 4096 + lq * 4);
        float* d = &sX[c * 69 + lq * 4];
        d[0] = v.x * ga + be; d[1] = v.y * ga + be; d[2] = v.z * ga + be; d[3] = v.w * ga + be;
    }
    __syncthreads();
    int lr = t >> 3, cp = t & 7;
    bf16* dst = xn_t + ((size_t)b * 4096 + l0) * 512 + c0;
    for (int i = 0; i < 2; ++i) {
        int l = lr + i * 32;
        bf16x8 o;
        for (int j = 0; j < 8; ++j) o[j] = (bf16)sX[(cp * 8 + j) * 69 + l];
        *(bf16x8*)(dst + (size_t)l * 512 + cp * 8) = o;
    }
}

// ---------------- MFMA GEMM: D[m][n] = sum_k A[m][k]*B[n][k], K=512, lda=ldb=512 ----------------
// Both operands row-major k-contiguous; staged via global_load_lds w/ XOR chunk swizzle.
__global__ __launch_bounds__(256) void k_gemm(
    const bf16* __restrict__ A, size_t aStride, const bf16* __restrict__ B, size_t bStride,
    const float* __restrict__ bias_m, const float* __restrict__ bias_n,
    bf16* __restrict__ outb, float* __restrict__ outf, const float* __restrict__ resid,
    int ldo, size_t oStride, float qscale, int qthresh) {
    __shared__ bf16 sA[128 * 64];
    __shared__ bf16 sB[128 * 64];
    int bz = blockIdx.z;
    const bf16* Ap = A + (size_t)bz * aStride;
    const bf16* Bp = B + (size_t)bz * bStride;
    int m0 = blockIdx.y * 128, n0 = blockIdx.x * 128;
    int tid = threadIdx.x, lane = tid & 63, wave = tid >> 6;
    int lo = lane & 15, quad = lane >> 4;
    int lr = lane >> 3, ls = lane & 7;
    int mw = (wave >> 1) * 64, nw = (wave & 1) * 64;
    f32x4 acc[4][4] = {};
    for (int k0 = 0; k0 < 512; k0 += 64) {
        for (int i = 0; i < 4; ++i) {
            int r0 = wave * 32 + i * 8;
            int row = r0 + lr;
            int gc = (ls ^ (row & 7)) * 8;
            gll16(Ap + (size_t)(m0 + row) * 512 + k0 + gc, &sA[r0 * 64]);
            gll16(Bp + (size_t)(n0 + row) * 512 + k0 + gc, &sB[r0 * 64]);
        }
        __syncthreads();
        for (int kk = 0; kk < 2; ++kk) {
            bf16x8 af[4], bfr[4];
            int sw = ((kk * 4 + quad) ^ (lo & 7)) * 8;
            for (int t = 0; t < 4; ++t) af[t]  = *(const bf16x8*)&sA[(mw + t * 16 + lo) * 64 + sw];
            for (int t = 0; t < 4; ++t) bfr[t] = *(const bf16x8*)&sB[(nw + t * 16 + lo) * 64 + sw];
            for (int mt = 0; mt < 4; ++mt)
                for (int nt = 0; nt < 4; ++nt)
                    acc[mt][nt] = __builtin_amdgcn_mfma_f32_16x16x32_bf16(af[mt], bfr[nt], acc[mt][nt], 0, 0, 0);
        }
        __syncthreads();
    }
    for (int mt = 0; mt < 4; ++mt) {
        int rowb = m0 + mw + mt * 16 + quad * 4;
        for (int nt = 0; nt < 4; ++nt) {
            int col = n0 + nw + nt * 16 + lo;
            float bn = bias_n ? bias_n[col] : 0.f;
            float sc = (col < qthresh) ? qscale : 1.f;
            for (int r = 0; r < 4; ++r) {
                int row = rowb + r;
                float bval = bias_m ? bias_m[row] : bn;
                float v = (acc[mt][nt][r] + bval) * sc;
                size_t idx = (size_t)bz * oStride + (size_t)row * ldo + col;
                if (outf) outf[idx] = v + resid[idx];
                else      outb[idx] = (bf16)v;
            }
        }
    }
}

// ---------------- flash attention ----------------
// qkT[b][l][1024] (q|k, q pre-scaled by QSCALE), v[b][512][4096] natural.
// grid (64, NH, B), block 256. Each wave owns 16 query rows end-to-end.
__global__ __launch_bounds__(256) void k_attn(const bf16* __restrict__ qkT, const bf16* __restrict__ vmat,
                                              bf16* __restrict__ attnT) {
    __shared__ __align__(16) char smem[41984];
    bf16* sK = (bf16*)smem;            // 64 x 128, chunk-swizzled by row&15 (Q staged here first)
    bf16* sV = (bf16*)(smem + 16384);  // 128 x 64, chunk-swizzled by row&7
    bf16* sP = (bf16*)(smem + 32768);  // 64 x 72
    int b = blockIdx.z, h = blockIdx.y, l0 = blockIdx.x * 64;
    int tid = threadIdx.x, lane = tid & 63, wave = tid >> 6;
    int lo = lane & 15, quad = lane >> 4;
    int lr16 = lane >> 4, ls16 = lane & 15;
    int lr8 = lane >> 3, ls8 = lane & 7;
    const bf16* qbase = qkT + (size_t)b * 4096 * 1024 + (size_t)l0 * 1024 + h * 128;
    const bf16* kbase = qkT + (size_t)b * 4096 * 1024 + 512 + h * 128;
    const bf16* vbase = vmat + (size_t)b * 512 * 4096 + (size_t)(h * 128) * 4096;
    // stage Q tile (reuse sK region), pull frags to regs
    for (int i = 0; i < 4; ++i) {
        int r0 = wave * 16 + i * 4;
        int row = r0 + lr16;
        gll16(qbase + (size_t)row * 1024 + ((ls16 ^ (row & 15)) * 8), &sK[r0 * 128]);
    }
    __syncthreads();
    bf16x8 qf[4];
    for (int kk = 0; kk < 4; ++kk)
        qf[kk] = *(const bf16x8*)&sK[(wave * 16 + lo) * 128 + (((kk * 4 + quad) ^ lo) * 8)];
    __syncthreads();   // all q-frag reads done before K staging overwrites
    float m_r[4], l_r[4];
    for (int r = 0; r < 4; ++r) { m_r[r] = -3e38f; l_r[r] = 0.f; }
    f32x4 oacc[8] = {};
    for (int e0 = 0; e0 < 4096; e0 += 64) {
        for (int i = 0; i < 4; ++i) {
            int r0 = wave * 16 + i * 4;
            int row = r0 + lr16;
            gll16(kbase + (size_t)(e0 + row) * 1024 + ((ls16 ^ (row & 15)) * 8), &sK[r0 * 128]);
        }
        for (int i = 0; i < 4; ++i) {
            int r0 = wave * 32 + i * 8;
            int row = r0 + lr8;
            gll16(vbase + (size_t)row * 4096 + e0 + ((ls8 ^ (row & 7)) * 8), &sV[r0 * 64]);
        }
        __syncthreads();
        // S = q . k (log2 domain), per wave: 16 queries x 64 keys, in registers
        f32x4 s[4];
        for (int nt = 0; nt < 4; ++nt) {
            f32x4 a = {};
            int key = nt * 16 + lo;
            for (int kk = 0; kk < 4; ++kk) {
                bf16x8 kf = *(const bf16x8*)&sK[key * 128 + (((kk * 4 + quad) ^ lo) * 8)];
                a = __builtin_amdgcn_mfma_f32_16x16x32_bf16(qf[kk], kf, a, 0, 0, 0);
            }
            s[nt] = a;
        }
        // register-space online softmax (rows: query = quad*4+r; reduce over lo lanes)
        float p[4][4];
        for (int r = 0; r < 4; ++r) {
            float mx = fmaxf(fmaxf(s[0][r], s[1][r]), fmaxf(s[2][r], s[3][r]));
            mx = fmaxf(mx, __shfl_xor(mx, 1));
            mx = fmaxf(mx, __shfl_xor(mx, 2));
            mx = fmaxf(mx, __shfl_xor(mx, 4));
            mx = fmaxf(mx, __shfl_xor(mx, 8));
            float m_new = fmaxf(m_r[r], mx);
            float al = exp2f(m_r[r] - m_new);
            float sm = 0.f;
            for (int nt = 0; nt < 4; ++nt) {
                float pv = exp2f(s[nt][r] - m_new);
                p[nt][r] = pv;
                sm += pv;
            }
            sm += __shfl_xor(sm, 1);
            sm += __shfl_xor(sm, 2);
            sm += __shfl_xor(sm, 4);
            sm += __shfl_xor(sm, 8);
            l_r[r] = l_r[r] * al + sm;
            m_r[r] = m_new;
            for (int nt2 = 0; nt2 < 8; ++nt2) oacc[nt2][r] *= al;
        }
        // P -> LDS (same-wave round trip, in-order LDS pipe; no barrier needed)
        for (int nt = 0; nt < 4; ++nt)
            for (int r = 0; r < 4; ++r)
                sP[(wave * 16 + quad * 4 + r) * 72 + nt * 16 + lo] = (bf16)p[nt][r];
        bf16x8 pf[2];
        for (int kk = 0; kk < 2; ++kk)
            pf[kk] = *(const bf16x8*)&sP[(wave * 16 + lo) * 72 + kk * 32 + quad * 8];
        // O[query][vchan] += P . V^T
        for (int nt2 = 0; nt2 < 8; ++nt2) {
            f32x4 o = oacc[nt2];
            int vc = nt2 * 16 + lo;
            for (int kk = 0; kk < 2; ++kk) {
                bf16x8 vf = *(const bf16x8*)&sV[vc * 64 + (((kk * 4 + quad) ^ (lo & 7)) * 8)];
                o = __builtin_amdgcn_mfma_f32_16x16x32_bf16(pf[kk], vf, o, 0, 0, 0);
            }
            oacc[nt2] = o;
        }
        __syncthreads();
    }
    // epilogue: normalize, LDS transpose-coalesce, write attnT[l][h*128..]
    __syncthreads();
    bf16* sO = (bf16*)smem;   // 64 x 136
    float inv[4];
    for (int r = 0; r < 4; ++r) inv[r] = 1.f / l_r[r];
    for (int nt2 = 0; nt2 < 8; ++nt2)
        for (int r = 0; r < 4; ++r)
            sO[(wave * 16 + quad * 4 + r) * 136 + nt2 * 16 + lo] = (bf16)(oacc[nt2][r] * inv[r]);
    __syncthreads();
    bf16* dst = attnT + ((size_t)b * 4096 + l0) * 512 + h * 128;
    for (int i = 0; i < 4; ++i) {
        int row = (tid >> 4) + i * 16;
        int chunk = tid & 15;
        bf16x8 v = *(const bf16x8*)&sO[row * 136 + chunk * 8];
        *(bf16x8*)(dst + (size_t)row * 512 + chunk * 8) = v;
    }
}

// ---------------- launcher ----------------
extern "C" void kernel_launch(void* const* d_in, const int* in_sizes, int n_in,
                              void* d_out, int out_size, void* d_ws, size_t ws_size,
                              hipStream_t stream) {
    const float* x      = (const float*)d_in[0];
    const float* gn_w   = (const float*)d_in[1];
    const float* gn_b   = (const float*)d_in[2];
    const float* w_qkv  = (const float*)d_in[3];
    const float* b_qkv  = (const float*)d_in[4];
    const float* w_proj = (const float*)d_in[5];
    const float* b_proj = (const float*)d_in[6];
    float* out = (float*)d_out;
    char* ws = (char*)d_ws;
    bf16* wqkv_b  = (bf16*)(ws + 0);          // 1,572,864
    bf16* wproj_b = (bf16*)(ws + 1572864);    //   524,288
    bf16* xn_t    = (bf16*)(ws + 2097152);    // 2*4096*512*2  = 8,388,608
    bf16* qkT     = (bf16*)(ws + 10485760);   // 2*4096*1024*2 = 16,777,216
    bf16* vb      = (bf16*)(ws + 27262976);   // 2*512*4096*2  = 8,388,608
    bf16* attnT   = (bf16*)(ws + 35651584);   // 2*4096*512*2  = 8,388,608
    float* part   = (float*)(ws + 44040192);
    float* gstats = (float*)(ws + 44042240);

    k_convert_w<<<1024, 256, 0, stream>>>(w_qkv, w_proj, wqkv_b, wproj_b);
    k_gn_partial<<<256, 256, 0, stream>>>(x, part);
    k_gn_final<<<1, 64, 0, stream>>>(part, gstats);
    k_gn_norm_t<<<dim3(64, 8, 2), 256, 0, stream>>>(x, gn_w, gn_b, gstats, xn_t);
    // qkT[b][l][o] = xn_t[l][.] . w_qkv[o][.] + b, o in [0,1024); q cols scaled by QSCALE
    k_gemm<<<dim3(8, 32, 2), 256, 0, stream>>>(xn_t, (size_t)4096 * 512, wqkv_b, (size_t)0,
                                               nullptr, b_qkv, qkT, nullptr, nullptr,
                                               1024, (size_t)4096 * 1024, QSCALE, 512);
    // v[b][c][l] = w_qkv[1024+c][.] . xn_t[l][.] + b
    k_gemm<<<dim3(32, 4, 2), 256, 0, stream>>>(wqkv_b + 1024 * 512, (size_t)0, xn_t, (size_t)4096 * 512,
                                               b_qkv + 1024, nullptr, vb, nullptr, nullptr,
                                               4096, (size_t)512 * 4096, 1.f, 0);
    k_attn<<<dim3(64, 4, 2), 256, 0, stream>>>(qkT, vb, attnT);
    // out[b][co][l] = w_proj[co][.] . attnT[l][.] + b + x
    k_gemm<<<dim3(32, 4, 2), 256, 0, stream>>>(wproj_b, (size_t)0, attnT, (size_t)4096 * 512,
                                               b_proj, nullptr, nullptr, out, x,
                                               4096, (size_t)512 * 4096, 1.f, 0);
}

// Round 3
// 308.568 us; speedup vs baseline: 1.4400x; 1.1950x over previous
//
#include <hip/hip_runtime.h>
#include <math.h>

typedef __bf16 bf16;
typedef __bf16 bf16x8 __attribute__((ext_vector_type(8)));
typedef __bf16 bf16x4 __attribute__((ext_vector_type(4)));
typedef float f32x4 __attribute__((ext_vector_type(4)));

// B=2, C=512, L=4096, NH=4, HD=128, GROUPS=32. K of every GEMM = 512.
#define QSCALE (0.08838834764831845f * 1.4426950408889634f)  // 1/sqrt(128) * log2(e)

__device__ __forceinline__ void gll16(const bf16* g, bf16* l) {
    __builtin_amdgcn_global_load_lds((const __attribute__((address_space(1))) void*)g,
                                     (__attribute__((address_space(3))) void*)l, 16, 0, 0);
}

// ---------------- weight conversion fp32 -> bf16 ----------------
__global__ void k_convert_w(const float* __restrict__ wqkv, const float* __restrict__ wproj,
                            bf16* __restrict__ wqkv_b, bf16* __restrict__ wproj_b) {
    int i = blockIdx.x * blockDim.x + threadIdx.x;   // float4 index
    const int n1 = (1536 * 512) / 4;
    float4 v;
    bf16* dst;
    if (i < n1) { v = ((const float4*)wqkv)[i];      dst = wqkv_b + (size_t)i * 4; }
    else        { v = ((const float4*)wproj)[i - n1]; dst = wproj_b + (size_t)(i - n1) * 4; }
    bf16x4 o;
    o[0] = (bf16)v.x; o[1] = (bf16)v.y; o[2] = (bf16)v.z; o[3] = (bf16)v.w;
    *(bf16x4*)dst = o;
}

// ---------------- GroupNorm stats ----------------
__global__ void k_gn_partial(const float* __restrict__ x, float* __restrict__ part) {
    int blk = blockIdx.x;
    int grp = blk >> 2, p = blk & 3;
    const float4* src = (const float4*)(x + (size_t)grp * 65536 + (size_t)p * 16384);
    float s = 0.f, ss = 0.f;
    for (int it = 0; it < 16; ++it) {
        float4 v = src[threadIdx.x + it * 256];
        s  += v.x + v.y + v.z + v.w;
        ss += v.x * v.x + v.y * v.y + v.z * v.z + v.w * v.w;
    }
    for (int off = 32; off; off >>= 1) { s += __shfl_down(s, off); ss += __shfl_down(ss, off); }
    __shared__ float rs[4], rss[4];
    int wave = threadIdx.x >> 6;
    if ((threadIdx.x & 63) == 0) { rs[wave] = s; rss[wave] = ss; }
    __syncthreads();
    if (threadIdx.x == 0) {
        part[(grp * 4 + p) * 2]     = rs[0] + rs[1] + rs[2] + rs[3];
        part[(grp * 4 + p) * 2 + 1] = rss[0] + rss[1] + rss[2] + rss[3];
    }
}

__global__ void k_gn_final(const float* __restrict__ part, float* __restrict__ gstats) {
    int g = threadIdx.x;   // 64 groups total (b*32+g)
    float S = 0.f, SS = 0.f;
    for (int p = 0; p < 4; ++p) { S += part[(g * 4 + p) * 2]; SS += part[(g * 4 + p) * 2 + 1]; }
    float mean = S * (1.f / 65536.f);
    float var  = SS * (1.f / 65536.f) - mean * mean;
    gstats[g * 2]     = mean;
    gstats[g * 2 + 1] = rsqrtf(var + 1e-5f);
}

// ---------------- GN normalize + transpose: x[b][c][l] -> xn_t[b][l][c] bf16 ----------------
__global__ __launch_bounds__(256) void k_gn_norm_t(const float* __restrict__ x, const float* __restrict__ gw,
                                                   const float* __restrict__ gb, const float* __restrict__ gstats,
                                                   bf16* __restrict__ xn_t) {
    __shared__ float sX[64 * 69];
    int b = blockIdx.z, c0 = blockIdx.y * 64, l0 = blockIdx.x * 64;
    int t = threadIdx.x;
    int cr = t >> 4, lq = t & 15;
    const float* xp = x + ((size_t)(b * 512 + c0)) * 4096 + l0;
    for (int i = 0; i < 4; ++i) {
        int c = cr + i * 16;
        int cg = c0 + c;
        int g = b * 32 + (cg >> 4);
        float mean = gstats[g * 2], rstd = gstats[g * 2 + 1];
        float ga = gw[cg] * rstd;
        float be = gb[cg] - mean * ga;
        float4 v = *(const float4*)(xp + (size_t)c * 4096 + lq * 4);
        float* d = &sX[c * 69 + lq * 4];
        d[0] = v.x * ga + be; d[1] = v.y * ga + be; d[2] = v.z * ga + be; d[3] = v.w * ga + be;
    }
    __syncthreads();
    int lr = t >> 3, cp = t & 7;
    bf16* dst = xn_t + ((size_t)b * 4096 + l0) * 512 + c0;
    for (int i = 0; i < 2; ++i) {
        int l = lr + i * 32;
        bf16x8 o;
        for (int j = 0; j < 8; ++j) o[j] = (bf16)sX[(cp * 8 + j) * 69 + l];
        *(bf16x8*)(dst + (size_t)l * 512 + cp * 8) = o;
    }
}

// ---------------- MFMA GEMM: D[m][n] = sum_k A[m][k]*B[n][k], K=512, lda=ldb=512 ----------------
// Double-buffered LDS w/ post-barrier prefetch; XOR chunk swizzle; BM = 128 or 64, BN = 128.
template<int BM>
__global__ __launch_bounds__(256) void k_gemm(
    const bf16* __restrict__ A, size_t aStride, const bf16* __restrict__ B, size_t bStride,
    const float* __restrict__ bias_m, const float* __restrict__ bias_n,
    bf16* __restrict__ outb, float* __restrict__ outf, const float* __restrict__ resid,
    int ldo, size_t oStride, float qscale, int qthresh) {
    constexpr int MT = BM / 32;          // m-tiles per wave (4 or 2)
    constexpr int NA = BM / 32;          // A-staging chunks per thread (4 or 2)
    constexpr int BUF = (BM + 128) * 64; // elems per buffer
    __shared__ bf16 smem[2 * BUF];
    int bz = blockIdx.z;
    int m0 = blockIdx.y * BM, n0 = blockIdx.x * 128;
    int tid = threadIdx.x, lane = tid & 63, wave = tid >> 6;
    int lo = lane & 15, quad = lane >> 4;
    int lr = lane >> 3, ls = lane & 7;
    int mw = (wave >> 1) * (BM / 2), nw = (wave & 1) * 64;
    // per-thread staging pointers (advance by 64 along k each step)
    const bf16* aptr[NA];
    int adst[NA];
    for (int i = 0; i < NA; ++i) {
        int r0 = wave * (BM / 4) + i * 8;
        int row = r0 + lr;
        aptr[i] = A + (size_t)bz * aStride + (size_t)(m0 + row) * 512 + ((ls ^ (row & 7)) * 8);
        adst[i] = r0 * 64;
    }
    const bf16* bptr[4];
    int bdst[4];
    for (int i = 0; i < 4; ++i) {
        int r0 = wave * 32 + i * 8;
        int row = r0 + lr;
        bptr[i] = B + (size_t)bz * bStride + (size_t)(n0 + row) * 512 + ((ls ^ (row & 7)) * 8);
        bdst[i] = BM * 64 + r0 * 64;
    }
    f32x4 acc[MT][4] = {};
    // prologue prefetch into buf 0
    for (int i = 0; i < NA; ++i) { gll16(aptr[i], &smem[adst[i]]); aptr[i] += 64; }
    for (int i = 0; i < 4;  ++i) { gll16(bptr[i], &smem[bdst[i]]); bptr[i] += 64; }
    for (int step = 0; step < 8; ++step) {
        int cur = step & 1;
        __syncthreads();   // drains vmcnt -> buf[cur] ready; prior reads of buf[cur^1] done
        if (step < 7) {
            bf16* nb = &smem[(cur ^ 1) * BUF];
            for (int i = 0; i < NA; ++i) { gll16(aptr[i], nb + adst[i]); aptr[i] += 64; }
            for (int i = 0; i < 4;  ++i) { gll16(bptr[i], nb + bdst[i]); bptr[i] += 64; }
        }
        const bf16* sA = &smem[cur * BUF];
        const bf16* sB = sA + BM * 64;
        for (int kk = 0; kk < 2; ++kk) {
            bf16x8 af[MT], bfr[4];
            int sw = ((kk * 4 + quad) ^ (lo & 7)) * 8;
            for (int t = 0; t < MT; ++t) af[t]  = *(const bf16x8*)&sA[(mw + t * 16 + lo) * 64 + sw];
            for (int t = 0; t < 4;  ++t) bfr[t] = *(const bf16x8*)&sB[(nw + t * 16 + lo) * 64 + sw];
            for (int mt = 0; mt < MT; ++mt)
                for (int nt = 0; nt < 4; ++nt)
                    acc[mt][nt] = __builtin_amdgcn_mfma_f32_16x16x32_bf16(af[mt], bfr[nt], acc[mt][nt], 0, 0, 0);
        }
    }
    for (int mt = 0; mt < MT; ++mt) {
        int rowb = m0 + mw + mt * 16 + quad * 4;
        for (int nt = 0; nt < 4; ++nt) {
            int col = n0 + nw + nt * 16 + lo;
            float bn = bias_n ? bias_n[col] : 0.f;
            float sc = (col < qthresh) ? qscale : 1.f;
            for (int r = 0; r < 4; ++r) {
                int row = rowb + r;
                float bval = bias_m ? bias_m[row] : bn;
                float v = (acc[mt][nt][r] + bval) * sc;
                size_t idx = (size_t)bz * oStride + (size_t)row * ldo + col;
                if (outf) outf[idx] = v + resid[idx];
                else      outb[idx] = (bf16)v;
            }
        }
    }
}

// ---------------- flash attention ----------------
// qkT[b][l][1024] (q|k, q pre-scaled), v[b][512][4096] natural. 1D grid 512, block 256.
// blockIdx&7 = (b,h): pins each head's 4MB K/V working set to one XCD's L2.
// Double-buffered K/V staging with post-barrier prefetch; each wave owns 16 query rows.
__global__ __launch_bounds__(256) void k_attn(const bf16* __restrict__ qkT, const bf16* __restrict__ vmat,
                                              bf16* __restrict__ attnT) {
    __shared__ __align__(16) char smem[75776];
    // sK[buf] @ buf*16384 (64x128), sV[buf] @ 32768+buf*16384 (128x64), sP @ 65536 (64x72)
    bf16* sP = (bf16*)(smem + 65536);
    int bidx = blockIdx.x;
    int bh = bidx & 7;
    int b = bh >> 2, h = bh & 3;
    int l0 = (bidx >> 3) * 64;
    int tid = threadIdx.x, lane = tid & 63, wave = tid >> 6;
    int lo = lane & 15, quad = lane >> 4;
    int lr16 = lane >> 4, ls16 = lane & 15;
    int lr8 = lane >> 3, ls8 = lane & 7;
    const bf16* qbase = qkT + (size_t)b * 4096 * 1024 + (size_t)l0 * 1024 + h * 128;
    const bf16* kbase = qkT + (size_t)b * 4096 * 1024 + 512 + h * 128;
    const bf16* vbase = vmat + (size_t)b * 512 * 4096 + (size_t)(h * 128) * 4096;
    // ---- stage Q tile into sK[0] region, pull frags to regs ----
    for (int i = 0; i < 4; ++i) {
        int r0 = wave * 16 + i * 4;
        int row = r0 + lr16;
        gll16(qbase + (size_t)row * 1024 + ((ls16 ^ (row & 15)) * 8), (bf16*)smem + r0 * 128);
    }
    __syncthreads();
    bf16x8 qf[4];
    for (int kk = 0; kk < 4; ++kk)
        qf[kk] = *(const bf16x8*)((bf16*)smem + (wave * 16 + lo) * 128 + (((kk * 4 + quad) ^ lo) * 8));
    __syncthreads();   // all q-frag reads done before K prefetch overwrites
    // ---- per-thread K/V staging pointers + LDS offsets ----
    const bf16* kptr[4]; int kdst[4];
    const bf16* vptr[4]; int vdst[4];
    for (int i = 0; i < 4; ++i) {
        int r0 = wave * 16 + i * 4;
        int row = r0 + lr16;
        kptr[i] = kbase + (size_t)row * 1024 + ((ls16 ^ (row & 15)) * 8);
        kdst[i] = r0 * 128;
        int s0 = wave * 32 + i * 8;
        int srow = s0 + lr8;
        vptr[i] = vbase + (size_t)srow * 4096 + ((ls8 ^ (srow & 7)) * 8);
        vdst[i] = 16384 + s0 * 64;   // elem offset with 32768-byte sV base /2
    }
    float m_r[4], l_r[4];
    for (int r = 0; r < 4; ++r) { m_r[r] = -3e38f; l_r[r] = 0.f; }
    f32x4 oacc[8] = {};
    // prologue prefetch (buf 0)
    for (int i = 0; i < 4; ++i) { gll16(kptr[i], (bf16*)smem + kdst[i]); kptr[i] += 64 * 1024; }
    for (int i = 0; i < 4; ++i) { gll16(vptr[i], (bf16*)smem + vdst[i]); vptr[i] += 64; }
    for (int it = 0; it < 64; ++it) {
        int cur = it & 1;
        __syncthreads();   // drains vmcnt: buf[cur] ready; readers of buf[cur^1] done
        if (it < 63) {
            bf16* nb = (bf16*)smem + (cur ^ 1) * 8192;
            for (int i = 0; i < 4; ++i) { gll16(kptr[i], nb + kdst[i]); kptr[i] += 64 * 1024; }
            for (int i = 0; i < 4; ++i) { gll16(vptr[i], nb + vdst[i]); vptr[i] += 64; }
        }
        const bf16* sK = (const bf16*)smem + cur * 8192;
        const bf16* sV = sK + 16384;
        // S = q . k (log2 domain): per wave 16 queries x 64 keys, in registers
        f32x4 s[4];
        for (int nt = 0; nt < 4; ++nt) {
            f32x4 a = {};
            int key = nt * 16 + lo;
            for (int kk = 0; kk < 4; ++kk) {
                bf16x8 kf = *(const bf16x8*)&sK[key * 128 + (((kk * 4 + quad) ^ lo) * 8)];
                a = __builtin_amdgcn_mfma_f32_16x16x32_bf16(qf[kk], kf, a, 0, 0, 0);
            }
            s[nt] = a;
        }
        // register online softmax (row = quad*4+r; reduce across lo lanes)
        float p[4][4];
        for (int r = 0; r < 4; ++r) {
            float mx = fmaxf(fmaxf(s[0][r], s[1][r]), fmaxf(s[2][r], s[3][r]));
            mx = fmaxf(mx, __shfl_xor(mx, 1));
            mx = fmaxf(mx, __shfl_xor(mx, 2));
            mx = fmaxf(mx, __shfl_xor(mx, 4));
            mx = fmaxf(mx, __shfl_xor(mx, 8));
            float m_new = fmaxf(m_r[r], mx);
            float al = exp2f(m_r[r] - m_new);
            float sm = 0.f;
            for (int nt = 0; nt < 4; ++nt) {
                float pv = exp2f(s[nt][r] - m_new);
                p[nt][r] = pv;
                sm += pv;
            }
            sm += __shfl_xor(sm, 1);
            sm += __shfl_xor(sm, 2);
            sm += __shfl_xor(sm, 4);
            sm += __shfl_xor(sm, 8);
            l_r[r] = l_r[r] * al + sm;
            m_r[r] = m_new;
            for (int nt2 = 0; nt2 < 8; ++nt2) oacc[nt2][r] *= al;
        }
        // P C-layout -> A-layout via same-wave LDS round trip (in-order pipe)
        for (int nt = 0; nt < 4; ++nt)
            for (int r = 0; r < 4; ++r)
                sP[(wave * 16 + quad * 4 + r) * 72 + nt * 16 + lo] = (bf16)p[nt][r];
        bf16x8 pf[2];
        for (int kk = 0; kk < 2; ++kk)
            pf[kk] = *(const bf16x8*)&sP[(wave * 16 + lo) * 72 + kk * 32 + quad * 8];
        // O[query][vchan] += P . V^T
        for (int nt2 = 0; nt2 < 8; ++nt2) {
            f32x4 o = oacc[nt2];
            int vc = nt2 * 16 + lo;
            for (int kk = 0; kk < 2; ++kk) {
                bf16x8 vf = *(const bf16x8*)&sV[vc * 64 + (((kk * 4 + quad) ^ (lo & 7)) * 8)];
                o = __builtin_amdgcn_mfma_f32_16x16x32_bf16(pf[kk], vf, o, 0, 0, 0);
            }
            oacc[nt2] = o;
        }
    }
    // epilogue: normalize, LDS transpose-coalesce, write attnT[l][h*128..]
    __syncthreads();
    bf16* sO = (bf16*)smem;   // 64 x 136
    float inv[4];
    for (int r = 0; r < 4; ++r) inv[r] = 1.f / l_r[r];
    for (int nt2 = 0; nt2 < 8; ++nt2)
        for (int r = 0; r < 4; ++r)
            sO[(wave * 16 + quad * 4 + r) * 136 + nt2 * 16 + lo] = (bf16)(oacc[nt2][r] * inv[r]);
    __syncthreads();
    bf16* dst = attnT + ((size_t)b * 4096 + l0) * 512 + h * 128;
    for (int i = 0; i < 4; ++i) {
        int row = (tid >> 4) + i * 16;
        int chunk = tid & 15;
        bf16x8 v = *(const bf16x8*)&sO[row * 136 + chunk * 8];
        *(bf16x8*)(dst + (size_t)row * 512 + chunk * 8) = v;
    }
}

// ---------------- launcher ----------------
extern "C" void kernel_launch(void* const* d_in, const int* in_sizes, int n_in,
                              void* d_out, int out_size, void* d_ws, size_t ws_size,
                              hipStream_t stream) {
    const float* x      = (const float*)d_in[0];
    const float* gn_w   = (const float*)d_in[1];
    const float* gn_b   = (const float*)d_in[2];
    const float* w_qkv  = (const float*)d_in[3];
    const float* b_qkv  = (const float*)d_in[4];
    const float* w_proj = (const float*)d_in[5];
    const float* b_proj = (const float*)d_in[6];
    float* out = (float*)d_out;
    char* ws = (char*)d_ws;
    bf16* wqkv_b  = (bf16*)(ws + 0);          // 1,572,864
    bf16* wproj_b = (bf16*)(ws + 1572864);    //   524,288
    bf16* xn_t    = (bf16*)(ws + 2097152);    // 2*4096*512*2  = 8,388,608
    bf16* qkT     = (bf16*)(ws + 10485760);   // 2*4096*1024*2 = 16,777,216
    bf16* vb      = (bf16*)(ws + 27262976);   // 2*512*4096*2  = 8,388,608
    bf16* attnT   = (bf16*)(ws + 35651584);   // 2*4096*512*2  = 8,388,608
    float* part   = (float*)(ws + 44040192);
    float* gstats = (float*)(ws + 44042240);

    k_convert_w<<<1024, 256, 0, stream>>>(w_qkv, w_proj, wqkv_b, wproj_b);
    k_gn_partial<<<256, 256, 0, stream>>>(x, part);
    k_gn_final<<<1, 64, 0, stream>>>(part, gstats);
    k_gn_norm_t<<<dim3(64, 8, 2), 256, 0, stream>>>(x, gn_w, gn_b, gstats, xn_t);
    // qkT[b][l][o] = xn_t[l][.] . w_qkv[o][.] + b, o in [0,1024); q cols scaled by QSCALE
    k_gemm<128><<<dim3(8, 32, 2), 256, 0, stream>>>(xn_t, (size_t)4096 * 512, wqkv_b, (size_t)0,
                                                    nullptr, b_qkv, qkT, nullptr, nullptr,
                                                    1024, (size_t)4096 * 1024, QSCALE, 512);
    // v[b][c][l] = w_qkv[1024+c][.] . xn_t[l][.] + b   (BM=64 -> 512 blocks, 2/CU)
    k_gemm<64><<<dim3(32, 8, 2), 256, 0, stream>>>(wqkv_b + 1024 * 512, (size_t)0, xn_t, (size_t)4096 * 512,
                                                   b_qkv + 1024, nullptr, vb, nullptr, nullptr,
                                                   4096, (size_t)512 * 4096, 1.f, 0);
    k_attn<<<512, 256, 0, stream>>>(qkT, vb, attnT);
    // out[b][co][l] = w_proj[co][.] . attnT[l][.] + b + x
    k_gemm<64><<<dim3(32, 8, 2), 256, 0, stream>>>(wproj_b, (size_t)0, attnT, (size_t)4096 * 512,
                                                   b_proj, nullptr, nullptr, out, x,
                                                   4096, (size_t)512 * 4096, 1.f, 0);
}

// Round 4
// 263.080 us; speedup vs baseline: 1.6890x; 1.1729x over previous
//
#include <hip/hip_runtime.h>
#include <math.h>

typedef __bf16 bf16;
typedef __bf16 bf16x8 __attribute__((ext_vector_type(8)));
typedef __bf16 bf16x4 __attribute__((ext_vector_type(4)));
typedef float f32x4 __attribute__((ext_vector_type(4)));

// B=2, C=512, L=4096, NH=4, HD=128, GROUPS=32. K of every GEMM = 512.
#define QSCALE (0.08838834764831845f * 1.4426950408889634f)  // 1/sqrt(128) * log2(e)

__device__ __forceinline__ void gll16(const bf16* g, bf16* l) {
    __builtin_amdgcn_global_load_lds((const __attribute__((address_space(1))) void*)g,
                                     (__attribute__((address_space(3))) void*)l, 16, 0, 0);
}

// ---------------- weight conversion fp32 -> bf16 ----------------
__global__ void k_convert_w(const float* __restrict__ wqkv, const float* __restrict__ wproj,
                            bf16* __restrict__ wqkv_b, bf16* __restrict__ wproj_b) {
    int i = blockIdx.x * blockDim.x + threadIdx.x;   // float4 index
    const int n1 = (1536 * 512) / 4;
    float4 v;
    bf16* dst;
    if (i < n1) { v = ((const float4*)wqkv)[i];      dst = wqkv_b + (size_t)i * 4; }
    else        { v = ((const float4*)wproj)[i - n1]; dst = wproj_b + (size_t)(i - n1) * 4; }
    bf16x4 o;
    o[0] = (bf16)v.x; o[1] = (bf16)v.y; o[2] = (bf16)v.z; o[3] = (bf16)v.w;
    *(bf16x4*)dst = o;
}

// ---------------- GroupNorm stats ----------------
__global__ void k_gn_partial(const float* __restrict__ x, float* __restrict__ part) {
    int blk = blockIdx.x;
    int grp = blk >> 2, p = blk & 3;
    const float4* src = (const float4*)(x + (size_t)grp * 65536 + (size_t)p * 16384);
    float s = 0.f, ss = 0.f;
    for (int it = 0; it < 16; ++it) {
        float4 v = src[threadIdx.x + it * 256];
        s  += v.x + v.y + v.z + v.w;
        ss += v.x * v.x + v.y * v.y + v.z * v.z + v.w * v.w;
    }
    for (int off = 32; off; off >>= 1) { s += __shfl_down(s, off); ss += __shfl_down(ss, off); }
    __shared__ float rs[4], rss[4];
    int wave = threadIdx.x >> 6;
    if ((threadIdx.x & 63) == 0) { rs[wave] = s; rss[wave] = ss; }
    __syncthreads();
    if (threadIdx.x == 0) {
        part[(grp * 4 + p) * 2]     = rs[0] + rs[1] + rs[2] + rs[3];
        part[(grp * 4 + p) * 2 + 1] = rss[0] + rss[1] + rss[2] + rss[3];
    }
}

__global__ void k_gn_final(const float* __restrict__ part, float* __restrict__ gstats) {
    int g = threadIdx.x;   // 64 groups total (b*32+g)
    float S = 0.f, SS = 0.f;
    for (int p = 0; p < 4; ++p) { S += part[(g * 4 + p) * 2]; SS += part[(g * 4 + p) * 2 + 1]; }
    float mean = S * (1.f / 65536.f);
    float var  = SS * (1.f / 65536.f) - mean * mean;
    gstats[g * 2]     = mean;
    gstats[g * 2 + 1] = rsqrtf(var + 1e-5f);
}

// ---------------- GN normalize + transpose: x[b][c][l] -> xn_t[b][l][c] bf16 ----------------
__global__ __launch_bounds__(256) void k_gn_norm_t(const float* __restrict__ x, const float* __restrict__ gw,
                                                   const float* __restrict__ gb, const float* __restrict__ gstats,
                                                   bf16* __restrict__ xn_t) {
    __shared__ float sX[64 * 69];
    int b = blockIdx.z, c0 = blockIdx.y * 64, l0 = blockIdx.x * 64;
    int t = threadIdx.x;
    int cr = t >> 4, lq = t & 15;
    const float* xp = x + ((size_t)(b * 512 + c0)) * 4096 + l0;
    for (int i = 0; i < 4; ++i) {
        int c = cr + i * 16;
        int cg = c0 + c;
        int g = b * 32 + (cg >> 4);
        float mean = gstats[g * 2], rstd = gstats[g * 2 + 1];
        float ga = gw[cg] * rstd;
        float be = gb[cg] - mean * ga;
        float4 v = *(const float4*)(xp + (size_t)c * 4096 + lq * 4);
        float* d = &sX[c * 69 + lq * 4];
        d[0] = v.x * ga + be; d[1] = v.y * ga + be; d[2] = v.z * ga + be; d[3] = v.w * ga + be;
    }
    __syncthreads();
    int lr = t >> 3, cp = t & 7;
    bf16* dst = xn_t + ((size_t)b * 4096 + l0) * 512 + c0;
    for (int i = 0; i < 2; ++i) {
        int l = lr + i * 32;
        bf16x8 o;
        for (int j = 0; j < 8; ++j) o[j] = (bf16)sX[(cp * 8 + j) * 69 + l];
        *(bf16x8*)(dst + (size_t)l * 512 + cp * 8) = o;
    }
}

// ---------------- MFMA GEMM: D[m][n] = sum_k A[m][k]*B[n][k], K=512, lda=ldb=512 ----------------
// Double-buffered LDS w/ post-barrier prefetch; XOR chunk swizzle; BM = 128 or 64, BN = 128.
template<int BM>
__global__ __launch_bounds__(256) void k_gemm(
    const bf16* __restrict__ A, size_t aStride, const bf16* __restrict__ B, size_t bStride,
    const float* __restrict__ bias_m, const float* __restrict__ bias_n,
    bf16* __restrict__ outb, float* __restrict__ outf, const float* __restrict__ resid,
    int ldo, size_t oStride, float qscale, int qthresh) {
    constexpr int MT = BM / 32;          // m-tiles per wave (4 or 2)
    constexpr int NA = BM / 32;          // A-staging chunks per thread (4 or 2)
    constexpr int BUF = (BM + 128) * 64; // elems per buffer
    __shared__ bf16 smem[2 * BUF];
    int bz = blockIdx.z;
    int m0 = blockIdx.y * BM, n0 = blockIdx.x * 128;
    int tid = threadIdx.x, lane = tid & 63, wave = tid >> 6;
    int lo = lane & 15, quad = lane >> 4;
    int lr = lane >> 3, ls = lane & 7;
    int mw = (wave >> 1) * (BM / 2), nw = (wave & 1) * 64;
    const bf16* aptr[NA];
    int adst[NA];
    for (int i = 0; i < NA; ++i) {
        int r0 = wave * (BM / 4) + i * 8;
        int row = r0 + lr;
        aptr[i] = A + (size_t)bz * aStride + (size_t)(m0 + row) * 512 + ((ls ^ (row & 7)) * 8);
        adst[i] = r0 * 64;
    }
    const bf16* bptr[4];
    int bdst[4];
    for (int i = 0; i < 4; ++i) {
        int r0 = wave * 32 + i * 8;
        int row = r0 + lr;
        bptr[i] = B + (size_t)bz * bStride + (size_t)(n0 + row) * 512 + ((ls ^ (row & 7)) * 8);
        bdst[i] = BM * 64 + r0 * 64;
    }
    f32x4 acc[MT][4] = {};
    for (int i = 0; i < NA; ++i) { gll16(aptr[i], &smem[adst[i]]); aptr[i] += 64; }
    for (int i = 0; i < 4;  ++i) { gll16(bptr[i], &smem[bdst[i]]); bptr[i] += 64; }
    for (int step = 0; step < 8; ++step) {
        int cur = step & 1;
        __syncthreads();
        if (step < 7) {
            bf16* nb = &smem[(cur ^ 1) * BUF];
            for (int i = 0; i < NA; ++i) { gll16(aptr[i], nb + adst[i]); aptr[i] += 64; }
            for (int i = 0; i < 4;  ++i) { gll16(bptr[i], nb + bdst[i]); bptr[i] += 64; }
        }
        const bf16* sA = &smem[cur * BUF];
        const bf16* sB = sA + BM * 64;
        for (int kk = 0; kk < 2; ++kk) {
            bf16x8 af[MT], bfr[4];
            int sw = ((kk * 4 + quad) ^ (lo & 7)) * 8;
            for (int t = 0; t < MT; ++t) af[t]  = *(const bf16x8*)&sA[(mw + t * 16 + lo) * 64 + sw];
            for (int t = 0; t < 4;  ++t) bfr[t] = *(const bf16x8*)&sB[(nw + t * 16 + lo) * 64 + sw];
            for (int mt = 0; mt < MT; ++mt)
                for (int nt = 0; nt < 4; ++nt)
                    acc[mt][nt] = __builtin_amdgcn_mfma_f32_16x16x32_bf16(af[mt], bfr[nt], acc[mt][nt], 0, 0, 0);
        }
    }
    for (int mt = 0; mt < MT; ++mt) {
        int rowb = m0 + mw + mt * 16 + quad * 4;
        for (int nt = 0; nt < 4; ++nt) {
            int col = n0 + nw + nt * 16 + lo;
            float bn = bias_n ? bias_n[col] : 0.f;
            float sc = (col < qthresh) ? qscale : 1.f;
            for (int r = 0; r < 4; ++r) {
                int row = rowb + r;
                float bval = bias_m ? bias_m[row] : bn;
                float v = (acc[mt][nt][r] + bval) * sc;
                size_t idx = (size_t)bz * oStride + (size_t)row * ldo + col;
                if (outf) outf[idx] = v + resid[idx];
                else      outb[idx] = (bf16)v;
            }
        }
    }
}

// ---------------- flash attention (split-key, S^T/O^T register softmax) ----------------
// qkT[b][l][1024] (q|k, q pre-scaled to log2 domain), v[b][512][4096] natural.
// 1D grid 512, block 256. blockIdx&7 = (b,h) pins each head's K/V to one XCD L2.
// Wave w = (key-half b2 = w>>1, q-half a = w&1): owns 32 queries x 32 keys of each tile.
// Private (m,l,O^T) per wave; single log-sum-exp merge at the end.
__global__ __launch_bounds__(256, 2) void k_attn(const bf16* __restrict__ qkT, const bf16* __restrict__ vmat,
                                                 bf16* __restrict__ attnT) {
    // LDS: sK dbuf [2][64][128] @0 (32KB) | sV dbuf [2][128][64] @32768 (32KB)
    //      sP [4 waves][32][40] @65536 (10KB) | sStat [64][2]{m,l} @75776 (1KB)
    //      merge reuse: sOm [2][128][33] f32 @0 (33KB), sOut [64][136] bf16 @34816 (17KB)
    __shared__ __align__(16) char smem[76800];
    bf16* sKbuf = (bf16*)smem;
    bf16* sVbuf = (bf16*)(smem + 32768);
    int bidx = blockIdx.x;
    int bh = bidx & 7;
    int bb = bh >> 2, h = bh & 3;
    int l0 = (bidx >> 3) * 64;
    int tid = threadIdx.x, lane = tid & 63, wave = tid >> 6;
    int lo = lane & 15, quad = lane >> 4;
    int a = wave & 1, b2 = wave >> 1;
    int lr16 = lane >> 4, ls16 = lane & 15;
    int lr8 = lane >> 3, ls8 = lane & 7;
    const bf16* qbase = qkT + ((size_t)bb * 4096 + l0) * 1024 + h * 128;
    const bf16* kbase = qkT + (size_t)bb * 4096 * 1024 + 512 + h * 128;
    const bf16* vbase = vmat + (size_t)(bb * 512 + h * 128) * 4096;
    // staging descriptors (wave-uniform LDS dests; lanes land at base + lane*16B)
    const bf16* kptr[4]; int kdst[4];
    const bf16* vptr[4]; int vdst[4];
    for (int i = 0; i < 4; ++i) {
        int r0 = wave * 16 + i * 4;
        int row = r0 + lr16;
        kptr[i] = kbase + (size_t)row * 1024 + ((ls16 ^ (row & 15)) * 8);
        kdst[i] = r0 * 128;
        int s0 = wave * 32 + i * 8;
        int srow = s0 + lr8;
        vptr[i] = vbase + (size_t)srow * 4096 + ((ls8 ^ (srow & 7)) * 8);
        vdst[i] = s0 * 64;
    }
    // prologue: Q -> sK buf1, K/V tile0 -> buf0
    for (int i = 0; i < 4; ++i) {
        int r0 = wave * 16 + i * 4;
        int row = r0 + lr16;
        gll16(qbase + (size_t)row * 1024 + ((ls16 ^ (row & 15)) * 8), sKbuf + 8192 + r0 * 128);
    }
    for (int i = 0; i < 4; ++i) { gll16(kptr[i], sKbuf + kdst[i]); kptr[i] += (size_t)64 * 1024; }
    for (int i = 0; i < 4; ++i) { gll16(vptr[i], sVbuf + vdst[i]); vptr[i] += 64; }
    __syncthreads();
    // Q frags (B-operand): q_local = a*32 + nt*16 + lo, k-chunk (kk*4+quad)^lo
    bf16x8 qf[2][4];
    for (int nt = 0; nt < 2; ++nt) {
        int row = a * 32 + nt * 16 + lo;
        for (int kk = 0; kk < 4; ++kk)
            qf[nt][kk] = *(const bf16x8*)&sKbuf[8192 + row * 128 + (((kk * 4 + quad) ^ lo) * 8)];
    }
    bf16* sPe = (bf16*)(smem + 65536) + wave * 1280;   // [32 q][40]
    float* sStat = (float*)(smem + 75776);             // [64 qb][2 halves] float2
    float m_r[2], l_r[2];
    m_r[0] = m_r[1] = -3e38f;
    l_r[0] = l_r[1] = 0.f;
    f32x4 oacc[8][2] = {};
    for (int it = 0; it < 64; ++it) {
        int cur = it & 1;
        __syncthreads();   // buf[cur] staged; prior readers of buf[cur^1] done (it=0: qf reads done)
        if (it < 63) {
            bf16* nk = sKbuf + (cur ^ 1) * 8192;
            bf16* nv = sVbuf + (cur ^ 1) * 4096;
            for (int i = 0; i < 4; ++i) { gll16(kptr[i], nk + kdst[i]); kptr[i] += (size_t)64 * 1024; }
            for (int i = 0; i < 4; ++i) { gll16(vptr[i], nv + vdst[i]); vptr[i] += 64; }
        }
        const bf16* sK = sKbuf + cur * 8192;
        const bf16* sV = sVbuf + cur * 4096;
        // S^T[key][q]: per wave 32 keys (its half) x 32 queries
        f32x4 s[2][2];
        for (int mt = 0; mt < 2; ++mt) {
            int krow = b2 * 32 + mt * 16 + lo;
            bf16x8 kf[4];
            for (int kk = 0; kk < 4; ++kk)
                kf[kk] = *(const bf16x8*)&sK[krow * 128 + (((kk * 4 + quad) ^ lo) * 8)];
            for (int nt = 0; nt < 2; ++nt) {
                f32x4 acc = {};
                for (int kk = 0; kk < 4; ++kk)
                    acc = __builtin_amdgcn_mfma_f32_16x16x32_bf16(kf[kk], qf[nt][kk], acc, 0, 0, 0);
                s[mt][nt] = acc;
            }
        }
        // register online softmax: lane holds 8 key-values per nt (query = nt*16+lo)
        float alpha[2];
        for (int nt = 0; nt < 2; ++nt) {
            float mx = fmaxf(fmaxf(fmaxf(s[0][nt][0], s[0][nt][1]), fmaxf(s[0][nt][2], s[0][nt][3])),
                             fmaxf(fmaxf(s[1][nt][0], s[1][nt][1]), fmaxf(s[1][nt][2], s[1][nt][3])));
            mx = fmaxf(mx, __shfl_xor(mx, 16));
            mx = fmaxf(mx, __shfl_xor(mx, 32));
            float m_new = fmaxf(m_r[nt], mx);
            alpha[nt] = exp2f(m_r[nt] - m_new);
            float sm = 0.f;
            for (int mt = 0; mt < 2; ++mt)
                for (int r = 0; r < 4; ++r) {
                    float pv = exp2f(s[mt][nt][r] - m_new);
                    s[mt][nt][r] = pv;
                    sm += pv;
                    sPe[(nt * 16 + lo) * 40 + mt * 16 + quad * 4 + r] = (bf16)pv;
                }
            sm += __shfl_xor(sm, 16);
            sm += __shfl_xor(sm, 32);
            l_r[nt] = l_r[nt] * alpha[nt] + sm;
            m_r[nt] = m_new;
        }
        if (__any(alpha[0] != 1.f || alpha[1] != 1.f)) {
            for (int mt2 = 0; mt2 < 8; ++mt2)
                for (int nt = 0; nt < 2; ++nt)
                    oacc[mt2][nt] *= alpha[nt];
        }
        // P frags (B-operand, same-wave LDS round trip)
        bf16x8 pf[2];
        for (int nt = 0; nt < 2; ++nt)
            pf[nt] = *(const bf16x8*)&sPe[(nt * 16 + lo) * 40 + quad * 8];
        // O^T[vc][q] += V . P  (A = V rows=vc, k = wave's 32-key half)
        for (int mt2 = 0; mt2 < 8; ++mt2) {
            bf16x8 vf = *(const bf16x8*)&sV[(mt2 * 16 + lo) * 64 + (((b2 * 4 + quad) ^ (lo & 7)) * 8)];
            for (int nt = 0; nt < 2; ++nt)
                oacc[mt2][nt] = __builtin_amdgcn_mfma_f32_16x16x32_bf16(vf, pf[nt], oacc[mt2][nt], 0, 0, 0);
        }
    }
    // ---- merge the two key-halves per q-half ----
    __syncthreads();
    if (quad == 0) {
        for (int nt = 0; nt < 2; ++nt) {
            int qb = a * 32 + nt * 16 + lo;
            sStat[(qb * 2 + b2) * 2]     = m_r[nt];
            sStat[(qb * 2 + b2) * 2 + 1] = l_r[nt];
        }
    }
    __syncthreads();
    float sc_self[2], inv[2];
    for (int nt = 0; nt < 2; ++nt) {
        int qb = a * 32 + nt * 16 + lo;
        float mp = sStat[(qb * 2 + (b2 ^ 1)) * 2];
        float lp = sStat[(qb * 2 + (b2 ^ 1)) * 2 + 1];
        float M = fmaxf(m_r[nt], mp);
        float ss = exp2f(m_r[nt] - M);
        float sp = exp2f(mp - M);
        sc_self[nt] = ss;
        inv[nt] = 1.f / (l_r[nt] * ss + lp * sp);
    }
    float* sOm = (float*)smem;            // [2 a][128 vc][33]
    bf16* sOut = (bf16*)(smem + 34816);   // [64 q][136]
    if (b2 == 1) {
        for (int mt2 = 0; mt2 < 8; ++mt2)
            for (int nt = 0; nt < 2; ++nt)
                for (int r = 0; r < 4; ++r) {
                    int vc = mt2 * 16 + quad * 4 + r;
                    sOm[a * 4224 + vc * 33 + nt * 16 + lo] = oacc[mt2][nt][r] * sc_self[nt];
                }
    }
    __syncthreads();
    if (b2 == 0) {
        for (int mt2 = 0; mt2 < 8; ++mt2)
            for (int nt = 0; nt < 2; ++nt)
                for (int r = 0; r < 4; ++r) {
                    int vc = mt2 * 16 + quad * 4 + r;
                    float v = (oacc[mt2][nt][r] * sc_self[nt] + sOm[a * 4224 + vc * 33 + nt * 16 + lo]) * inv[nt];
                    sOut[(a * 32 + nt * 16 + lo) * 136 + vc] = (bf16)v;
                }
    }
    __syncthreads();
    bf16* dst = attnT + ((size_t)bb * 4096 + l0) * 512 + h * 128;
    for (int i = 0; i < 4; ++i) {
        int row = (tid >> 4) + i * 16;
        int chunk = tid & 15;
        bf16x8 v = *(const bf16x8*)&sOut[row * 136 + chunk * 8];
        *(bf16x8*)(dst + (size_t)row * 512 + chunk * 8) = v;
    }
}

// ---------------- launcher ----------------
extern "C" void kernel_launch(void* const* d_in, const int* in_sizes, int n_in,
                              void* d_out, int out_size, void* d_ws, size_t ws_size,
                              hipStream_t stream) {
    const float* x      = (const float*)d_in[0];
    const float* gn_w   = (const float*)d_in[1];
    const float* gn_b   = (const float*)d_in[2];
    const float* w_qkv  = (const float*)d_in[3];
    const float* b_qkv  = (const float*)d_in[4];
    const float* w_proj = (const float*)d_in[5];
    const float* b_proj = (const float*)d_in[6];
    float* out = (float*)d_out;
    char* ws = (char*)d_ws;
    bf16* wqkv_b  = (bf16*)(ws + 0);
    bf16* wproj_b = (bf16*)(ws + 1572864);
    bf16* xn_t    = (bf16*)(ws + 2097152);
    bf16* qkT     = (bf16*)(ws + 10485760);
    bf16* vb      = (bf16*)(ws + 27262976);
    bf16* attnT   = (bf16*)(ws + 35651584);
    float* part   = (float*)(ws + 44040192);
    float* gstats = (float*)(ws + 44042240);

    k_convert_w<<<1024, 256, 0, stream>>>(w_qkv, w_proj, wqkv_b, wproj_b);
    k_gn_partial<<<256, 256, 0, stream>>>(x, part);
    k_gn_final<<<1, 64, 0, stream>>>(part, gstats);
    k_gn_norm_t<<<dim3(64, 8, 2), 256, 0, stream>>>(x, gn_w, gn_b, gstats, xn_t);
    k_gemm<128><<<dim3(8, 32, 2), 256, 0, stream>>>(xn_t, (size_t)4096 * 512, wqkv_b, (size_t)0,
                                                    nullptr, b_qkv, qkT, nullptr, nullptr,
                                                    1024, (size_t)4096 * 1024, QSCALE, 512);
    k_gemm<64><<<dim3(32, 8, 2), 256, 0, stream>>>(wqkv_b + 1024 * 512, (size_t)0, xn_t, (size_t)4096 * 512,
                                                   b_qkv + 1024, nullptr, vb, nullptr, nullptr,
                                                   4096, (size_t)512 * 4096, 1.f, 0);
    k_attn<<<512, 256, 0, stream>>>(qkT, vb, attnT);
    k_gemm<64><<<dim3(32, 8, 2), 256, 0, stream>>>(wproj_b, (size_t)0, attnT, (size_t)4096 * 512,
                                                   b_proj, nullptr, nullptr, out, x,
                                                   4096, (size_t)512 * 4096, 1.f, 0);
}